// Round 5
// baseline (1119.035 us; speedup 1.0000x reference)
//
#include <hip/hip_runtime.h>
#include <math.h>

#define HW 65536

// ---------- tables: cosT/sinT[k][x] (16x256) and ET[j][x] (32x256, j=2k:cos, j=2k+1:-sin) ----------
__global__ __launch_bounds__(256) void k_tables(float* __restrict__ cosT, float* __restrict__ sinT,
                                                float* __restrict__ ET) {
  int idx = blockIdx.x * 256 + threadIdx.x;   // 48*256 = 12288 >= 4096 + 8192
  const float w = 0.0245436926061702596f;     // 2*pi/256
  if (idx < 4096) {
    int k = idx >> 8, xx = idx & 255;
    int t = (k * xx) & 255;
    float ang = (float)t * w;
    cosT[idx] = cosf(ang);
    sinT[idx] = sinf(ang);
  } else if (idx < 12288) {
    int e = idx - 4096;
    int j = e >> 8, xx = e & 255;
    int k = j >> 1;
    int t = (k * xx) & 255;
    float ang = (float)t * w;
    ET[e] = (j & 1) ? -sinf(ang) : cosf(ang);
  }
}

// ---------- fc0: (B,3,H,W) -> (B,64,H,W) ----------
__global__ __launch_bounds__(256) void k_fc0(const float* __restrict__ x, const float* __restrict__ w,
                                             const float* __restrict__ b, float* __restrict__ h) {
  int bid = blockIdx.x;                 // 1024 = B*H
  int bb = bid >> 8, y = bid & 255;
  int tx = threadIdx.x;
  __shared__ float ws[192];
  __shared__ float bs[64];
  if (tx < 192) ws[tx] = w[tx];
  if (tx < 64) bs[tx] = b[tx];
  __syncthreads();
  const float* xp = x + ((bb * 3) * 256 + y) * 256 + tx;
  float v0 = xp[0], v1 = xp[HW], v2 = xp[2 * HW];
  float* hp = h + ((bb * 64) * 256 + y) * 256 + tx;
#pragma unroll 4
  for (int o = 0; o < 64; ++o) {
    hp[o * HW] = bs[o] + ws[o * 3] * v0 + ws[o * 3 + 1] * v1 + ws[o * 3 + 2] * v2;
  }
}

// ---------- F1 as register-tiled GEMM: A[r][k] (float2), r = (b*64+c)*256+y ----------
// 512 blocks x 128 rows. Thread tile 4m x 4n.
__global__ __launch_bounds__(256) void k_f1(const float* __restrict__ h, const float* __restrict__ ET,
                                            float2* __restrict__ A) {
  __shared__ float es[32 * 260];   // E^T padded
  __shared__ float hs[128 * 36];   // 128 rows x 32 k-chunk, padded stride 36
  int tid = threadIdx.x;
  int tm = tid & 31, tn = tid >> 5;
  int r0 = blockIdx.x * 128;
  int base = r0 * 256;
#pragma unroll
  for (int rep = 0; rep < 8; ++rep) {
    int flat = rep * 256 + tid;
    *(float4*)&es[(flat >> 6) * 260 + (flat & 63) * 4] = ((const float4*)ET)[flat];
  }
  float4 st[4];
  {
    const float4* hp = (const float4*)(h + base);
#pragma unroll
    for (int q = 0; q < 4; ++q) {
      int flat = q * 256 + tid;
      st[q] = hp[(flat >> 3) * 64 + (flat & 7)];
    }
  }
  float acc[4][4];
#pragma unroll
  for (int i = 0; i < 4; ++i)
#pragma unroll
    for (int p = 0; p < 4; ++p) acc[i][p] = 0.f;

  for (int xc = 0; xc < 8; ++xc) {
    __syncthreads();
#pragma unroll
    for (int q = 0; q < 4; ++q) {
      int flat = q * 256 + tid;
      *(float4*)&hs[(flat >> 3) * 36 + (flat & 7) * 4] = st[q];
    }
    __syncthreads();
    if (xc < 7) {
      const float4* hp = (const float4*)(h + base);
#pragma unroll
      for (int q = 0; q < 4; ++q) {
        int flat = q * 256 + tid;
        st[q] = hp[(flat >> 3) * 64 + (xc + 1) * 8 + (flat & 7)];
      }
    }
    int xbase = xc * 32;
#pragma unroll
    for (int kk = 0; kk < 32; kk += 4) {
      float4 e0 = *(const float4*)&es[(tn * 4 + 0) * 260 + xbase + kk];
      float4 e1 = *(const float4*)&es[(tn * 4 + 1) * 260 + xbase + kk];
      float4 e2 = *(const float4*)&es[(tn * 4 + 2) * 260 + xbase + kk];
      float4 e3 = *(const float4*)&es[(tn * 4 + 3) * 260 + xbase + kk];
#pragma unroll
      for (int i = 0; i < 4; ++i) {
        float4 hv = *(const float4*)&hs[(tm + 32 * i) * 36 + kk];
        acc[i][0] += hv.x * e0.x + hv.y * e0.y + hv.z * e0.z + hv.w * e0.w;
        acc[i][1] += hv.x * e1.x + hv.y * e1.y + hv.z * e1.z + hv.w * e1.w;
        acc[i][2] += hv.x * e2.x + hv.y * e2.y + hv.z * e2.z + hv.w * e2.w;
        acc[i][3] += hv.x * e3.x + hv.y * e3.y + hv.z * e3.z + hv.w * e3.w;
      }
    }
  }
#pragma unroll
  for (int i = 0; i < 4; ++i) {
    int r = r0 + tm + 32 * i;
    *(float4*)&A[r * 16 + tn * 2] = make_float4(acc[i][0], acc[i][1], acc[i][2], acc[i][3]);
  }
}

// ---------- F2: col DFT over y, LDS-staged ----------
__global__ __launch_bounds__(256) void k_f2(const float2* __restrict__ A, const float* __restrict__ cosT,
                                            const float* __restrict__ sinT, float2* __restrict__ X) {
  int plane = blockIdx.x;               // 256 = B*C
  int tid = threadIdx.x;
  __shared__ float2 As[256 * 16];       // 32 KB
  __shared__ float ct[16 * 257];
  __shared__ float stt[16 * 257];
  const float2* Ap = A + plane * 4096;
#pragma unroll
  for (int rep = 0; rep < 16; ++rep) {
    int flat = rep * 256 + tid;
    As[flat] = Ap[flat];
  }
#pragma unroll
  for (int rep = 0; rep < 16; ++rep) {
    int flat = rep * 256 + tid;
    int ky = flat >> 8, y = flat & 255;
    ct[ky * 257 + y] = cosT[flat];
    stt[ky * 257 + y] = sinT[flat];
  }
  __syncthreads();
  int ky = tid >> 4, kx = tid & 15;
  float xr = 0.f, xi = 0.f;
#pragma unroll 4
  for (int y = 0; y < 256; ++y) {
    float2 a = As[y * 16 + kx];
    float c = ct[ky * 257 + y], s = stt[ky * 257 + y];
    xr += c * a.x + s * a.y;
    xi += c * a.y - s * a.x;
  }
  X[plane * 256 + tid] = make_float2(xr, xi);
}

// ---------- MIX: Y[b,o,m] = sum_c X[b,c,m] * (wr+i wi)[c,o,m], c split 4-way in-block ----------
__global__ __launch_bounds__(256) void k_mix(const float2* __restrict__ X, const float* __restrict__ wr,
                                             const float* __restrict__ wi, float2* __restrict__ Y) {
  int o = blockIdx.x >> 2;              // 64 o * 4 m-chunks
  int mc = blockIdx.x & 3;
  int tid = threadIdx.x;
  int cg = tid >> 6, m2 = tid & 63;
  int m = mc * 64 + m2;
  float yr[4] = {0.f, 0.f, 0.f, 0.f}, yi[4] = {0.f, 0.f, 0.f, 0.f};
#pragma unroll 4
  for (int cc = 0; cc < 16; ++cc) {
    int c = cg * 16 + cc;
    float r = wr[(c * 64 + o) * 256 + m];
    float im = wi[(c * 64 + o) * 256 + m];
#pragma unroll
    for (int b = 0; b < 4; ++b) {
      float2 xv = X[(b * 64 + c) * 256 + m];
      yr[b] += xv.x * r - xv.y * im;
      yi[b] += xv.x * im + xv.y * r;
    }
  }
  __shared__ float2 red[1024];
#pragma unroll
  for (int b = 0; b < 4; ++b) red[cg * 256 + b * 64 + m2] = make_float2(yr[b], yi[b]);
  __syncthreads();
  int b = tid >> 6;
  float sx = 0.f, sy = 0.f;
#pragma unroll
  for (int g2 = 0; g2 < 4; ++g2) {
    float2 v = red[g2 * 256 + b * 64 + m2];
    sx += v.x; sy += v.y;
  }
  Y[(b * 64 + o) * 256 + m] = make_float2(sx, sy);
}

// ---------- INV1: g[b,o,y,kx] = sum_ky Y[b,o,ky,kx] e^{+2pi i ky y/256}, scaled ----------
__global__ __launch_bounds__(256) void k_inv1(const float2* __restrict__ Y, const float* __restrict__ cosT,
                                              const float* __restrict__ sinT, float2* __restrict__ g) {
  int plane = blockIdx.x;               // 256 = B*O
  int y = threadIdx.x;
  __shared__ float2 Ys[256];
  Ys[threadIdx.x] = Y[plane * 256 + threadIdx.x];
  __syncthreads();
  float gr[16], gi[16];
#pragma unroll
  for (int k = 0; k < 16; ++k) { gr[k] = 0.f; gi[k] = 0.f; }
  for (int ky = 0; ky < 16; ++ky) {
    float c = cosT[ky * 256 + y], s = sinT[ky * 256 + y];
#pragma unroll
    for (int kx = 0; kx < 16; ++kx) {
      float2 v = Ys[ky * 16 + kx];
      gr[kx] += c * v.x - s * v.y;
      gi[kx] += c * v.y + s * v.x;
    }
  }
  float2* gp = g + (plane * 256 + y) * 16;
  const float sc = 1.0f / 65536.0f;
#pragma unroll
  for (int kx = 0; kx < 16; ++kx) {
    float m = (kx == 0) ? sc : 2.0f * sc;
    gp[kx] = make_float2(gr[kx] * m, gi[kx] * m);
  }
}

// ---------- K_LAYER: hout = GELU( [W^T | g] x [h ; ET] + wb ) ----------
// K=96 GEMM per (b,y,x-half): 64o x 128x tile, thread 8o x 4x. Grid 2048.
__global__ __launch_bounds__(256) void k_layer(const float* __restrict__ h, const float* __restrict__ g,
                                               const float* __restrict__ ww, const float* __restrict__ wb,
                                               const float* __restrict__ ET, float* __restrict__ hout) {
  int bid = blockIdx.x;                 // 2048 = b*512 + y*2 + xh
  int b = bid >> 9, y = (bid >> 1) & 255, xh = bid & 1;
  int tid = threadIdx.x;
  int to = tid >> 5, tx = tid & 31;
  int o0 = to * 8;
  __shared__ float As[96 * 65];         // 24.4 KB, stride 65 (== 1 mod 32)
  __shared__ float Bs[16 * 128];        // 8 KB

  // stage A: W^T (rows 0-63), then g (rows 64-95).
#pragma unroll
  for (int p = 0; p < 16; ++p) {
    int flat = p * 256 + tid;
    As[(flat & 63) * 65 + (flat >> 6)] = ww[flat];
  }
#pragma unroll
  for (int p = 0; p < 8; ++p) {
    int flat = p * 256 + tid;
    As[(64 + (flat & 31)) * 65 + (flat >> 5)] =
        g[(size_t)(b * 64 + (flat >> 5)) * 8192 + y * 32 + (flat & 31)];
  }

  const float4* hb = (const float4*)(h + (size_t)b * 64 * HW + y * 256);
  const float4* et4 = (const float4*)ET;

  float acc[8][4];
#pragma unroll
  for (int i = 0; i < 8; ++i)
#pragma unroll
    for (int j = 0; j < 4; ++j) acc[i][j] = 0.f;

  float4 st[2];
#pragma unroll
  for (int q = 0; q < 2; ++q) {
    int flat = q * 256 + tid;
    st[q] = hb[(size_t)(flat >> 5) * 16384 + xh * 32 + (flat & 31)];
  }

  for (int ch = 0; ch < 6; ++ch) {
    __syncthreads();
#pragma unroll
    for (int q = 0; q < 2; ++q) {
      int flat = q * 256 + tid;
      *(float4*)&Bs[(flat >> 5) * 128 + (flat & 31) * 4] = st[q];
    }
    __syncthreads();
    if (ch < 5) {
      int nc = ch + 1;
#pragma unroll
      for (int q = 0; q < 2; ++q) {
        int flat = q * 256 + tid;
        int row = flat >> 5, c4 = flat & 31;
        st[q] = (nc < 4) ? hb[(size_t)(nc * 16 + row) * 16384 + xh * 32 + c4]
                         : et4[((nc - 4) * 16 + row) * 64 + xh * 32 + c4];
      }
    }
    int kb = ch * 16;
#pragma unroll
    for (int k = 0; k < 16; ++k) {
      const float* ar = &As[(kb + k) * 65 + o0];
      float4 a0 = *(const float4*)ar;
      float4 a1 = *(const float4*)(ar + 4);
      float4 b0 = *(const float4*)&Bs[k * 128 + tx * 4];
      float av[8] = {a0.x, a0.y, a0.z, a0.w, a1.x, a1.y, a1.z, a1.w};
      float bv[4] = {b0.x, b0.y, b0.z, b0.w};
#pragma unroll
      for (int i = 0; i < 8; ++i)
#pragma unroll
        for (int j = 0; j < 4; ++j) acc[i][j] += av[i] * bv[j];
    }
  }
#pragma unroll
  for (int i = 0; i < 8; ++i) {
    int o = o0 + i;
    float bia = wb[o];
    float r[4];
#pragma unroll
    for (int j = 0; j < 4; ++j) {
      float v = acc[i][j] + bia;
      r[j] = 0.5f * v * (1.0f + erff(v * 0.70710678118654752f));
    }
    *(float4*)&hout[(size_t)(b * 64 + o) * HW + y * 256 + xh * 128 + tx * 4] =
        make_float4(r[0], r[1], r[2], r[3]);
  }
}

// ---------- K_FINAL: out = fc2( GELU( fc1(h) ) ), 128-x tiles, j in 2 halves ----------
__global__ __launch_bounds__(256) void k_final(const float* __restrict__ h, const float* __restrict__ w1,
                                               const float* __restrict__ b1, const float* __restrict__ w2,
                                               const float* __restrict__ b2, float* __restrict__ out) {
  int bid = blockIdx.x;                 // 2048 = b*512 + y*2 + xh
  int b = bid >> 9, y = (bid >> 1) & 255, xh = bid & 1;
  int tid = threadIdx.x;
  int to = tid >> 5, tx = tid & 31;
  int j0 = to * 8;
  __shared__ float As[64 * 65];         // 16.6 KB
  __shared__ float Bs[16 * 128];        // 8 KB; aliased as red[8*132] at the end

  const float4* hb = (const float4*)(h + (size_t)b * 64 * HW + y * 256);

  float p[4] = {0.f, 0.f, 0.f, 0.f};

  for (int jh = 0; jh < 2; ++jh) {
    if (jh) __syncthreads();            // protect As from previous half's readers
#pragma unroll
    for (int pq = 0; pq < 16; ++pq) {
      int flat = pq * 256 + tid;
      As[(flat & 63) * 65 + (flat >> 6)] = w1[(jh * 64 + (flat >> 6)) * 64 + (flat & 63)];
    }
    float acc[8][4];
#pragma unroll
    for (int i = 0; i < 8; ++i)
#pragma unroll
      for (int j = 0; j < 4; ++j) acc[i][j] = 0.f;

    float4 st[2];
#pragma unroll
    for (int q = 0; q < 2; ++q) {
      int flat = q * 256 + tid;
      st[q] = hb[(size_t)(flat >> 5) * 16384 + xh * 32 + (flat & 31)];
    }
    for (int ch = 0; ch < 4; ++ch) {
      __syncthreads();
#pragma unroll
      for (int q = 0; q < 2; ++q) {
        int flat = q * 256 + tid;
        *(float4*)&Bs[(flat >> 5) * 128 + (flat & 31) * 4] = st[q];
      }
      __syncthreads();
      if (ch < 3) {
#pragma unroll
        for (int q = 0; q < 2; ++q) {
          int flat = q * 256 + tid;
          st[q] = hb[(size_t)((ch + 1) * 16 + (flat >> 5)) * 16384 + xh * 32 + (flat & 31)];
        }
      }
      int kb = ch * 16;
#pragma unroll
      for (int k = 0; k < 16; ++k) {
        const float* ar = &As[(kb + k) * 65 + j0];
        float4 a0 = *(const float4*)ar;
        float4 a1 = *(const float4*)(ar + 4);
        float4 b0 = *(const float4*)&Bs[k * 128 + tx * 4];
        float av[8] = {a0.x, a0.y, a0.z, a0.w, a1.x, a1.y, a1.z, a1.w};
        float bv[4] = {b0.x, b0.y, b0.z, b0.w};
#pragma unroll
        for (int i = 0; i < 8; ++i)
#pragma unroll
          for (int j = 0; j < 4; ++j) acc[i][j] += av[i] * bv[j];
      }
    }
#pragma unroll
    for (int i = 0; i < 8; ++i) {
      int j = jh * 64 + j0 + i;
      float bia = b1[j], f2 = w2[j];
#pragma unroll
      for (int q = 0; q < 4; ++q) {
        float v = acc[i][q] + bia;
        float r = 0.5f * v * (1.0f + erff(v * 0.70710678118654752f));
        p[q] += f2 * r;
      }
    }
  }
  float* red = Bs;                      // reuse (all Bs reads are done after barrier)
  __syncthreads();
  *(float4*)&red[to * 132 + tx * 4] = make_float4(p[0], p[1], p[2], p[3]);
  __syncthreads();
  if (tid < 128) {
    float s = 0.f;
#pragma unroll
    for (int t = 0; t < 8; ++t) s += red[t * 132 + tid];
    out[(b * 256 + y) * 256 + xh * 128 + tid] = s + b2[0];
  }
}

extern "C" void kernel_launch(void* const* d_in, const int* in_sizes, int n_in,
                              void* d_out, int out_size, void* d_ws, size_t ws_size,
                              hipStream_t stream) {
  const float* x       = (const float*)d_in[0];
  const float* fc0_w   = (const float*)d_in[1];
  const float* fc0_b   = (const float*)d_in[2];
  const float* spec_wr = (const float*)d_in[3];
  const float* spec_wi = (const float*)d_in[4];
  const float* w_w     = (const float*)d_in[5];
  const float* w_b     = (const float*)d_in[6];
  const float* fc1_w   = (const float*)d_in[7];
  const float* fc1_b   = (const float*)d_in[8];
  const float* fc2_w   = (const float*)d_in[9];
  const float* fc2_b   = (const float*)d_in[10];
  float* out = (float*)d_out;

  char* ws = (char*)d_ws;
  float*  h0   = (float*)ws;                               // 67108864 B
  float*  h1   = (float*)(ws + 67108864);                  // 67108864 B
  float2* A    = (float2*)(ws + 134217728);                // 8388608 B
  float*  g    = (float*)(ws + 142606336);                 // 8388608 B
  float2* X    = (float2*)(ws + 150994944);                // 524288 B
  float2* Y    = (float2*)(ws + 151519232);                // 524288 B
  float*  cosT = (float*)(ws + 152043520);                 // 16384 B
  float*  sinT = cosT + 4096;                              // 16384 B
  float*  ET   = sinT + 4096;                              // 32768 B

  k_tables<<<48, 256, 0, stream>>>(cosT, sinT, ET);
  k_fc0<<<1024, 256, 0, stream>>>(x, fc0_w, fc0_b, h0);
  float* hc = h0; float* hn = h1;
  for (int l = 0; l < 4; ++l) {
    k_f1<<<512, 256, 0, stream>>>(hc, ET, A);
    k_f2<<<256, 256, 0, stream>>>(A, cosT, sinT, X);
    k_mix<<<256, 256, 0, stream>>>(X, spec_wr + (size_t)l * 1048576, spec_wi + (size_t)l * 1048576, Y);
    k_inv1<<<256, 256, 0, stream>>>(Y, cosT, sinT, (float2*)g);
    k_layer<<<2048, 256, 0, stream>>>(hc, g, w_w + l * 4096, w_b + l * 64, ET, hn);
    float* t = hc; hc = hn; hn = t;
  }
  k_final<<<2048, 256, 0, stream>>>(hc, fc1_w, fc1_b, fc2_w, fc2_b, out);
}

// Round 6
// 644.821 us; speedup vs baseline: 1.7354x; 1.7354x over previous
//
#include <hip/hip_runtime.h>
#include <math.h>

#define HW 65536

typedef __attribute__((ext_vector_type(8))) short short8;
typedef __attribute__((ext_vector_type(4))) float f32x4;

__device__ __forceinline__ unsigned bf16rne(float f) {
  union { float f; unsigned u; } a; a.f = f;
  return (a.u + 0x7fffu + ((a.u >> 16) & 1u)) >> 16;
}
__device__ __forceinline__ float bf16tof(unsigned h) {
  union { unsigned u; float f; } a; a.u = h << 16;
  return a.f;
}
__device__ __forceinline__ void split8(const float* f, short8& hi, short8& lo) {
#pragma unroll
  for (int i = 0; i < 8; ++i) {
    unsigned h = bf16rne(f[i]);
    float r = f[i] - bf16tof(h);
    hi[i] = (short)h;
    lo[i] = (short)bf16rne(r);
  }
}
__device__ __forceinline__ float gelu(float v) {
  return 0.5f * v * (1.0f + erff(v * 0.70710678118654752f));
}

// ---------- tables: cosT/sinT[k][x] (16x256) and ET[j][x] (32x256, j=2k:cos, j=2k+1:-sin) ----------
__global__ __launch_bounds__(256) void k_tables(float* __restrict__ cosT, float* __restrict__ sinT,
                                                float* __restrict__ ET) {
  int idx = blockIdx.x * 256 + threadIdx.x;
  const float w = 0.0245436926061702596f;     // 2*pi/256
  if (idx < 4096) {
    int k = idx >> 8, xx = idx & 255;
    int t = (k * xx) & 255;
    float ang = (float)t * w;
    cosT[idx] = cosf(ang);
    sinT[idx] = sinf(ang);
  } else if (idx < 12288) {
    int e = idx - 4096;
    int j = e >> 8, xx = e & 255;
    int k = j >> 1;
    int t = (k * xx) & 255;
    float ang = (float)t * w;
    ET[e] = (j & 1) ? -sinf(ang) : cosf(ang);
  }
}

// ---------- fc0: (B,3,H,W) -> (B,64,H,W) ----------
__global__ __launch_bounds__(256) void k_fc0(const float* __restrict__ x, const float* __restrict__ w,
                                             const float* __restrict__ b, float* __restrict__ h) {
  int bid = blockIdx.x;                 // 1024 = B*H
  int bb = bid >> 8, y = bid & 255;
  int tx = threadIdx.x;
  __shared__ float ws[192];
  __shared__ float bs[64];
  if (tx < 192) ws[tx] = w[tx];
  if (tx < 64) bs[tx] = b[tx];
  __syncthreads();
  const float* xp = x + ((bb * 3) * 256 + y) * 256 + tx;
  float v0 = xp[0], v1 = xp[HW], v2 = xp[2 * HW];
  float* hp = h + ((bb * 64) * 256 + y) * 256 + tx;
#pragma unroll 4
  for (int o = 0; o < 64; ++o) {
    hp[o * HW] = bs[o] + ws[o * 3] * v0 + ws[o * 3 + 1] * v1 + ws[o * 3 + 2] * v2;
  }
}

// ---------- F1 as register-tiled GEMM: A[r][k] (float2), r = (b*64+c)*256+y ----------
__global__ __launch_bounds__(256) void k_f1(const float* __restrict__ h, const float* __restrict__ ET,
                                            float2* __restrict__ A) {
  __shared__ float es[32 * 260];
  __shared__ float hs[128 * 36];
  int tid = threadIdx.x;
  int tm = tid & 31, tn = tid >> 5;
  int r0 = blockIdx.x * 128;
  int base = r0 * 256;
#pragma unroll
  for (int rep = 0; rep < 8; ++rep) {
    int flat = rep * 256 + tid;
    *(float4*)&es[(flat >> 6) * 260 + (flat & 63) * 4] = ((const float4*)ET)[flat];
  }
  float4 st[4];
  {
    const float4* hp = (const float4*)(h + base);
#pragma unroll
    for (int q = 0; q < 4; ++q) {
      int flat = q * 256 + tid;
      st[q] = hp[(flat >> 3) * 64 + (flat & 7)];
    }
  }
  float acc[4][4];
#pragma unroll
  for (int i = 0; i < 4; ++i)
#pragma unroll
    for (int p = 0; p < 4; ++p) acc[i][p] = 0.f;

  for (int xc = 0; xc < 8; ++xc) {
    __syncthreads();
#pragma unroll
    for (int q = 0; q < 4; ++q) {
      int flat = q * 256 + tid;
      *(float4*)&hs[(flat >> 3) * 36 + (flat & 7) * 4] = st[q];
    }
    __syncthreads();
    if (xc < 7) {
      const float4* hp = (const float4*)(h + base);
#pragma unroll
      for (int q = 0; q < 4; ++q) {
        int flat = q * 256 + tid;
        st[q] = hp[(flat >> 3) * 64 + (xc + 1) * 8 + (flat & 7)];
      }
    }
    int xbase = xc * 32;
#pragma unroll
    for (int kk = 0; kk < 32; kk += 4) {
      float4 e0 = *(const float4*)&es[(tn * 4 + 0) * 260 + xbase + kk];
      float4 e1 = *(const float4*)&es[(tn * 4 + 1) * 260 + xbase + kk];
      float4 e2 = *(const float4*)&es[(tn * 4 + 2) * 260 + xbase + kk];
      float4 e3 = *(const float4*)&es[(tn * 4 + 3) * 260 + xbase + kk];
#pragma unroll
      for (int i = 0; i < 4; ++i) {
        float4 hv = *(const float4*)&hs[(tm + 32 * i) * 36 + kk];
        acc[i][0] += hv.x * e0.x + hv.y * e0.y + hv.z * e0.z + hv.w * e0.w;
        acc[i][1] += hv.x * e1.x + hv.y * e1.y + hv.z * e1.z + hv.w * e1.w;
        acc[i][2] += hv.x * e2.x + hv.y * e2.y + hv.z * e2.z + hv.w * e2.w;
        acc[i][3] += hv.x * e3.x + hv.y * e3.y + hv.z * e3.z + hv.w * e3.w;
      }
    }
  }
#pragma unroll
  for (int i = 0; i < 4; ++i) {
    int r = r0 + tm + 32 * i;
    *(float4*)&A[r * 16 + tn * 2] = make_float4(acc[i][0], acc[i][1], acc[i][2], acc[i][3]);
  }
}

// ---------- F2: col DFT over y, LDS-staged ----------
__global__ __launch_bounds__(256) void k_f2(const float2* __restrict__ A, const float* __restrict__ cosT,
                                            const float* __restrict__ sinT, float2* __restrict__ X) {
  int plane = blockIdx.x;
  int tid = threadIdx.x;
  __shared__ float2 As[256 * 16];
  __shared__ float ct[16 * 257];
  __shared__ float stt[16 * 257];
  const float2* Ap = A + plane * 4096;
#pragma unroll
  for (int rep = 0; rep < 16; ++rep) {
    int flat = rep * 256 + tid;
    As[flat] = Ap[flat];
  }
#pragma unroll
  for (int rep = 0; rep < 16; ++rep) {
    int flat = rep * 256 + tid;
    int ky = flat >> 8, y = flat & 255;
    ct[ky * 257 + y] = cosT[flat];
    stt[ky * 257 + y] = sinT[flat];
  }
  __syncthreads();
  int ky = tid >> 4, kx = tid & 15;
  float xr = 0.f, xi = 0.f;
#pragma unroll 4
  for (int y = 0; y < 256; ++y) {
    float2 a = As[y * 16 + kx];
    float c = ct[ky * 257 + y], s = stt[ky * 257 + y];
    xr += c * a.x + s * a.y;
    xi += c * a.y - s * a.x;
  }
  X[plane * 256 + tid] = make_float2(xr, xi);
}

// ---------- MIX ----------
__global__ __launch_bounds__(256) void k_mix(const float2* __restrict__ X, const float* __restrict__ wr,
                                             const float* __restrict__ wi, float2* __restrict__ Y) {
  int o = blockIdx.x >> 2;
  int mc = blockIdx.x & 3;
  int tid = threadIdx.x;
  int cg = tid >> 6, m2 = tid & 63;
  int m = mc * 64 + m2;
  float yr[4] = {0.f, 0.f, 0.f, 0.f}, yi[4] = {0.f, 0.f, 0.f, 0.f};
#pragma unroll 4
  for (int cc = 0; cc < 16; ++cc) {
    int c = cg * 16 + cc;
    float r = wr[(c * 64 + o) * 256 + m];
    float im = wi[(c * 64 + o) * 256 + m];
#pragma unroll
    for (int b = 0; b < 4; ++b) {
      float2 xv = X[(b * 64 + c) * 256 + m];
      yr[b] += xv.x * r - xv.y * im;
      yi[b] += xv.x * im + xv.y * r;
    }
  }
  __shared__ float2 red[1024];
#pragma unroll
  for (int b = 0; b < 4; ++b) red[cg * 256 + b * 64 + m2] = make_float2(yr[b], yi[b]);
  __syncthreads();
  int b = tid >> 6;
  float sx = 0.f, sy = 0.f;
#pragma unroll
  for (int g2 = 0; g2 < 4; ++g2) {
    float2 v = red[g2 * 256 + b * 64 + m2];
    sx += v.x; sy += v.y;
  }
  Y[(b * 64 + o) * 256 + m] = make_float2(sx, sy);
}

// ---------- INV1 ----------
__global__ __launch_bounds__(256) void k_inv1(const float2* __restrict__ Y, const float* __restrict__ cosT,
                                              const float* __restrict__ sinT, float2* __restrict__ g) {
  int plane = blockIdx.x;
  int y = threadIdx.x;
  __shared__ float2 Ys[256];
  Ys[threadIdx.x] = Y[plane * 256 + threadIdx.x];
  __syncthreads();
  float gr[16], gi[16];
#pragma unroll
  for (int k = 0; k < 16; ++k) { gr[k] = 0.f; gi[k] = 0.f; }
  for (int ky = 0; ky < 16; ++ky) {
    float c = cosT[ky * 256 + y], s = sinT[ky * 256 + y];
#pragma unroll
    for (int kx = 0; kx < 16; ++kx) {
      float2 v = Ys[ky * 16 + kx];
      gr[kx] += c * v.x - s * v.y;
      gi[kx] += c * v.y + s * v.x;
    }
  }
  float2* gp = g + (plane * 256 + y) * 16;
  const float sc = 1.0f / 65536.0f;
#pragma unroll
  for (int kx = 0; kx < 16; ++kx) {
    float m = (kx == 0) ? sc : 2.0f * sc;
    gp[kx] = make_float2(gr[kx] * m, gi[kx] * m);
  }
}

// ---------- K_LAYER (MFMA split-bf16): hout = GELU( [W | g] x [h ; ET] + wb ) ----------
// Block=(b,y,xh): M=64 o, N=128 x, K=96. 4 waves x (2 N-frags). A direct-from-global,
// B via L1 fp32 transpose -> Bs bf16 hi/lo rows [x][40 ushort] (80B stride, <=2-way).
__global__ __launch_bounds__(256) void k_layer(const float* __restrict__ h, const float* __restrict__ g,
                                               const float* __restrict__ ww, const float* __restrict__ wb,
                                               const float* __restrict__ ET, float* __restrict__ hout) {
  int bid = blockIdx.x;                 // 2048 = b*512 + y*2 + xh
  int b = bid >> 9, y = (bid >> 1) & 255, xh = bid & 1;
  int tid = threadIdx.x;
  int lane = tid & 63, wave = tid >> 6;
  int lm = lane & 15, lg = lane >> 4;
  __shared__ float L1[32 * 132];
  __shared__ ushort BsH[128 * 40];
  __shared__ ushort BsL[128 * 40];

  const float* hbase = h + (size_t)b * 64 * HW + y * 256 + xh * 128;

  f32x4 acc[4][2];
#pragma unroll
  for (int mi = 0; mi < 4; ++mi)
#pragma unroll
    for (int ni = 0; ni < 2; ++ni) acc[mi][ni] = (f32x4){0.f, 0.f, 0.f, 0.f};

  float4 st[4];
#define LDSTAGE_L(kc_)                                                              \
  {                                                                                 \
    _Pragma("unroll") for (int q = 0; q < 4; ++q) {                                 \
      int idx = q * 256 + tid; int k = idx >> 5, xo = idx & 31;                     \
      const float* src = ((kc_) < 2) ? (hbase + (size_t)((kc_)*32 + k) * HW + xo*4) \
                                     : (ET + k * 256 + xh * 128 + xo * 4);          \
      st[q] = *(const float4*)src;                                                  \
    }                                                                               \
  }
  LDSTAGE_L(0);

  for (int kc = 0; kc < 3; ++kc) {
    __syncthreads();
#pragma unroll
    for (int q = 0; q < 4; ++q) {
      int idx = q * 256 + tid; int k = idx >> 5, xo = idx & 31;
      *(float4*)&L1[k * 132 + xo * 4] = st[q];
    }
    __syncthreads();
    {
      int x = tid & 127, oh = tid >> 7;
#pragma unroll
      for (int oc = 0; oc < 2; ++oc) {
        int oct = oh * 2 + oc;
        float f[8];
#pragma unroll
        for (int j = 0; j < 8; ++j) f[j] = L1[(oct * 8 + j) * 132 + x];
        short8 hi, lo; split8(f, hi, lo);
        int sidx = x * 40 + oct * 8;
        *(short8*)&BsH[sidx] = hi;
        *(short8*)&BsL[sidx] = lo;
      }
    }
    __syncthreads();
    if (kc == 0) LDSTAGE_L(1)
    else if (kc == 1) LDSTAGE_L(2)

    short8 bh[2], bl[2];
#pragma unroll
    for (int ni = 0; ni < 2; ++ni) {
      int xb = wave * 32 + ni * 16 + lm;
      int si = xb * 40 + lg * 8;
      bh[ni] = *(const short8*)&BsH[si];
      bl[ni] = *(const short8*)&BsL[si];
    }
#pragma unroll
    for (int mi = 0; mi < 4; ++mi) {
      int o = mi * 16 + lm;
      const float* ap = (kc < 2) ? (ww + o * 64 + kc * 32 + lg * 8)
                                 : (g + ((size_t)(b * 64 + o) * 256 + y) * 32 + lg * 8);
      float4 a0 = *(const float4*)ap, a1 = *(const float4*)(ap + 4);
      float f[8] = {a0.x, a0.y, a0.z, a0.w, a1.x, a1.y, a1.z, a1.w};
      short8 ah, al; split8(f, ah, al);
#pragma unroll
      for (int ni = 0; ni < 2; ++ni) {
        acc[mi][ni] = __builtin_amdgcn_mfma_f32_16x16x32_bf16(ah, bh[ni], acc[mi][ni], 0, 0, 0);
        acc[mi][ni] = __builtin_amdgcn_mfma_f32_16x16x32_bf16(ah, bl[ni], acc[mi][ni], 0, 0, 0);
        acc[mi][ni] = __builtin_amdgcn_mfma_f32_16x16x32_bf16(al, bh[ni], acc[mi][ni], 0, 0, 0);
      }
    }
  }
#undef LDSTAGE_L

#pragma unroll
  for (int mi = 0; mi < 4; ++mi)
#pragma unroll
    for (int r = 0; r < 4; ++r) {
      int o = mi * 16 + lg * 4 + r;
      float bia = wb[o];
#pragma unroll
      for (int ni = 0; ni < 2; ++ni) {
        float v = acc[mi][ni][r] + bia;
        hout[(size_t)(b * 64 + o) * HW + y * 256 + xh * 128 + wave * 32 + ni * 16 + lm] = gelu(v);
      }
    }
}

// ---------- K_FINAL (MFMA split-bf16): out = fc2( GELU( fc1(h) ) ) ----------
// Block=(b,y,xh): M=128 j, N=128 x, K=64.
__global__ __launch_bounds__(256) void k_final(const float* __restrict__ h, const float* __restrict__ w1,
                                               const float* __restrict__ b1, const float* __restrict__ w2,
                                               const float* __restrict__ b2, float* __restrict__ out) {
  int bid = blockIdx.x;                 // 2048 = b*512 + y*2 + xh
  int b = bid >> 9, y = (bid >> 1) & 255, xh = bid & 1;
  int tid = threadIdx.x;
  int lane = tid & 63, wave = tid >> 6;
  int lm = lane & 15, lg = lane >> 4;
  __shared__ float L1[32 * 132];
  __shared__ ushort BsH[128 * 40];
  __shared__ ushort BsL[128 * 40];

  const float* hbase = h + (size_t)b * 64 * HW + y * 256 + xh * 128;

  f32x4 acc[8][2];
#pragma unroll
  for (int mi = 0; mi < 8; ++mi)
#pragma unroll
    for (int ni = 0; ni < 2; ++ni) acc[mi][ni] = (f32x4){0.f, 0.f, 0.f, 0.f};

  float4 st[4];
#define LDSTAGE_F(kc_)                                                \
  {                                                                   \
    _Pragma("unroll") for (int q = 0; q < 4; ++q) {                   \
      int idx = q * 256 + tid; int k = idx >> 5, xo = idx & 31;       \
      st[q] = *(const float4*)(hbase + (size_t)((kc_)*32 + k) * HW + xo * 4); \
    }                                                                 \
  }
  LDSTAGE_F(0);

  for (int kc = 0; kc < 2; ++kc) {
    __syncthreads();
#pragma unroll
    for (int q = 0; q < 4; ++q) {
      int idx = q * 256 + tid; int k = idx >> 5, xo = idx & 31;
      *(float4*)&L1[k * 132 + xo * 4] = st[q];
    }
    __syncthreads();
    {
      int x = tid & 127, oh = tid >> 7;
#pragma unroll
      for (int oc = 0; oc < 2; ++oc) {
        int oct = oh * 2 + oc;
        float f[8];
#pragma unroll
        for (int j = 0; j < 8; ++j) f[j] = L1[(oct * 8 + j) * 132 + x];
        short8 hi, lo; split8(f, hi, lo);
        int sidx = x * 40 + oct * 8;
        *(short8*)&BsH[sidx] = hi;
        *(short8*)&BsL[sidx] = lo;
      }
    }
    __syncthreads();
    if (kc == 0) LDSTAGE_F(1)

    short8 bh[2], bl[2];
#pragma unroll
    for (int ni = 0; ni < 2; ++ni) {
      int xb = wave * 32 + ni * 16 + lm;
      int si = xb * 40 + lg * 8;
      bh[ni] = *(const short8*)&BsH[si];
      bl[ni] = *(const short8*)&BsL[si];
    }
#pragma unroll
    for (int mi = 0; mi < 8; ++mi) {
      const float* ap = w1 + (mi * 16 + lm) * 64 + kc * 32 + lg * 8;
      float4 a0 = *(const float4*)ap, a1 = *(const float4*)(ap + 4);
      float f[8] = {a0.x, a0.y, a0.z, a0.w, a1.x, a1.y, a1.z, a1.w};
      short8 ah, al; split8(f, ah, al);
#pragma unroll
      for (int ni = 0; ni < 2; ++ni) {
        acc[mi][ni] = __builtin_amdgcn_mfma_f32_16x16x32_bf16(ah, bh[ni], acc[mi][ni], 0, 0, 0);
        acc[mi][ni] = __builtin_amdgcn_mfma_f32_16x16x32_bf16(ah, bl[ni], acc[mi][ni], 0, 0, 0);
        acc[mi][ni] = __builtin_amdgcn_mfma_f32_16x16x32_bf16(al, bh[ni], acc[mi][ni], 0, 0, 0);
      }
    }
  }
#undef LDSTAGE_F

  float p0 = 0.f, p1 = 0.f;
#pragma unroll
  for (int mi = 0; mi < 8; ++mi)
#pragma unroll
    for (int r = 0; r < 4; ++r) {
      int j = mi * 16 + lg * 4 + r;
      float bj = b1[j], wj = w2[j];
      p0 += wj * gelu(acc[mi][0][r] + bj);
      p1 += wj * gelu(acc[mi][1][r] + bj);
    }
  p0 += __shfl_xor(p0, 16);
  p0 += __shfl_xor(p0, 32);
  p1 += __shfl_xor(p1, 16);
  p1 += __shfl_xor(p1, 32);
  if (lg == 0) {
    float bb2 = b2[0];
    int ob = (b * 256 + y) * 256 + xh * 128 + wave * 32;
    out[ob + lm] = p0 + bb2;
    out[ob + 16 + lm] = p1 + bb2;
  }
}

extern "C" void kernel_launch(void* const* d_in, const int* in_sizes, int n_in,
                              void* d_out, int out_size, void* d_ws, size_t ws_size,
                              hipStream_t stream) {
  const float* x       = (const float*)d_in[0];
  const float* fc0_w   = (const float*)d_in[1];
  const float* fc0_b   = (const float*)d_in[2];
  const float* spec_wr = (const float*)d_in[3];
  const float* spec_wi = (const float*)d_in[4];
  const float* w_w     = (const float*)d_in[5];
  const float* w_b     = (const float*)d_in[6];
  const float* fc1_w   = (const float*)d_in[7];
  const float* fc1_b   = (const float*)d_in[8];
  const float* fc2_w   = (const float*)d_in[9];
  const float* fc2_b   = (const float*)d_in[10];
  float* out = (float*)d_out;

  char* ws = (char*)d_ws;
  float*  h0   = (float*)ws;                               // 67108864 B
  float*  h1   = (float*)(ws + 67108864);                  // 67108864 B
  float2* A    = (float2*)(ws + 134217728);                // 8388608 B
  float*  g    = (float*)(ws + 142606336);                 // 8388608 B
  float2* X    = (float2*)(ws + 150994944);                // 524288 B
  float2* Y    = (float2*)(ws + 151519232);                // 524288 B
  float*  cosT = (float*)(ws + 152043520);                 // 16384 B
  float*  sinT = cosT + 4096;                              // 16384 B
  float*  ET   = sinT + 4096;                              // 32768 B

  k_tables<<<48, 256, 0, stream>>>(cosT, sinT, ET);
  k_fc0<<<1024, 256, 0, stream>>>(x, fc0_w, fc0_b, h0);
  float* hc = h0; float* hn = h1;
  for (int l = 0; l < 4; ++l) {
    k_f1<<<512, 256, 0, stream>>>(hc, ET, A);
    k_f2<<<256, 256, 0, stream>>>(A, cosT, sinT, X);
    k_mix<<<256, 256, 0, stream>>>(X, spec_wr + (size_t)l * 1048576, spec_wi + (size_t)l * 1048576, Y);
    k_inv1<<<256, 256, 0, stream>>>(Y, cosT, sinT, (float2*)g);
    k_layer<<<2048, 256, 0, stream>>>(hc, g, w_w + l * 4096, w_b + l * 64, ET, hn);
    float* t = hc; hc = hn; hn = t;
  }
  k_final<<<2048, 256, 0, stream>>>(hc, fc1_w, fc1_b, fc2_w, fc2_b, out);
}

// Round 7
// 605.681 us; speedup vs baseline: 1.8476x; 1.0646x over previous
//
#include <hip/hip_runtime.h>
#include <math.h>

#define HW 65536

typedef __attribute__((ext_vector_type(8))) short short8;
typedef __attribute__((ext_vector_type(4))) float f32x4;

__device__ __forceinline__ unsigned bf16rne(float f) {
  union { float f; unsigned u; } a; a.f = f;
  return (a.u + 0x7fffu + ((a.u >> 16) & 1u)) >> 16;
}
__device__ __forceinline__ float bf16tof(unsigned h) {
  union { unsigned u; float f; } a; a.u = h << 16;
  return a.f;
}
__device__ __forceinline__ float gelu(float v) {
  return 0.5f * v * (1.0f + erff(v * 0.70710678118654752f));
}

// ---------- tables: cosT/sinT fp32 (16x256); ETA hi/lo [32][256]; ET2 hi/lo [256][32] ----------
__global__ __launch_bounds__(256) void k_tables(float* __restrict__ cosT, float* __restrict__ sinT,
                                                ushort* __restrict__ eah, ushort* __restrict__ eal,
                                                ushort* __restrict__ e2h, ushort* __restrict__ e2l) {
  int idx = blockIdx.x * 256 + threadIdx.x;
  const float w = 0.0245436926061702596f;     // 2*pi/256
  if (idx < 4096) {
    int k = idx >> 8, xx = idx & 255;
    int t = (k * xx) & 255;
    float ang = (float)t * w;
    cosT[idx] = cosf(ang);
    sinT[idx] = sinf(ang);
  } else if (idx < 12288) {
    int e = idx - 4096;
    int j = e >> 8, xx = e & 255;
    int k = j >> 1;
    int t = (k * xx) & 255;
    float ang = (float)t * w;
    float val = (j & 1) ? -sinf(ang) : cosf(ang);
    unsigned hi = bf16rne(val);
    unsigned lo = bf16rne(val - bf16tof(hi));
    eah[j * 256 + xx] = (ushort)hi;
    eal[j * 256 + xx] = (ushort)lo;
    e2h[xx * 32 + j] = (ushort)hi;
    e2l[xx * 32 + j] = (ushort)lo;
  }
}

// ---------- wsplit: pre-split w_w (4x64x64) and fc1_w (128x64) ----------
__global__ __launch_bounds__(256) void k_wsplit(const float* __restrict__ ww, const float* __restrict__ w1,
                                                ushort* __restrict__ wh, ushort* __restrict__ wl,
                                                ushort* __restrict__ w1h, ushort* __restrict__ w1l) {
  int idx = blockIdx.x * 256 + threadIdx.x;   // 96*256 = 24576
  if (idx < 16384) {
    float v = ww[idx];
    unsigned hi = bf16rne(v);
    wh[idx] = (ushort)hi;
    wl[idx] = (ushort)bf16rne(v - bf16tof(hi));
  } else if (idx < 24576) {
    int j = idx - 16384;
    float v = w1[j];
    unsigned hi = bf16rne(v);
    w1h[j] = (ushort)hi;
    w1l[j] = (ushort)bf16rne(v - bf16tof(hi));
  }
}

// ---------- fc0: (B,3,H,W) -> h[n][c] split planes ----------
__global__ __launch_bounds__(256) void k_fc0(const float* __restrict__ x, const float* __restrict__ w,
                                             const float* __restrict__ b,
                                             ushort* __restrict__ hh, ushort* __restrict__ hl) {
  int bid = blockIdx.x;                 // 1024 = B*H
  int bb = bid >> 8, y = bid & 255;
  int tx = threadIdx.x;
  __shared__ float ws[192];
  __shared__ float bs[64];
  if (tx < 192) ws[tx] = w[tx];
  if (tx < 64) bs[tx] = b[tx];
  __syncthreads();
  const float* xp = x + ((bb * 3) * 256 + y) * 256 + tx;
  float v0 = xp[0], v1 = xp[HW], v2 = xp[2 * HW];
  size_t n = (size_t)bid * 256 + tx;
#pragma unroll 4
  for (int o4 = 0; o4 < 16; ++o4) {
    ushort4 H, L;
    float vv[4];
#pragma unroll
    for (int q = 0; q < 4; ++q) {
      int o = o4 * 4 + q;
      vv[q] = bs[o] + ws[o * 3] * v0 + ws[o * 3 + 1] * v1 + ws[o * 3 + 2] * v2;
    }
    unsigned h0 = bf16rne(vv[0]), h1 = bf16rne(vv[1]), h2 = bf16rne(vv[2]), h3 = bf16rne(vv[3]);
    H = make_ushort4((ushort)h0, (ushort)h1, (ushort)h2, (ushort)h3);
    L = make_ushort4((ushort)bf16rne(vv[0] - bf16tof(h0)), (ushort)bf16rne(vv[1] - bf16tof(h1)),
                     (ushort)bf16rne(vv[2] - bf16tof(h2)), (ushort)bf16rne(vv[3] - bf16tof(h3)));
    *(ushort4*)&hh[n * 64 + o4 * 4] = H;
    *(ushort4*)&hl[n * 64 + o4 * 4] = L;
  }
}

// ---------- F1 (MFMA): per (b,y), A1[kspec=32][c=64] = E^T[32][256] x h[256][64] ----------
// Writes old layout A[(b*64+c)*256+y][32 floats].
__global__ __launch_bounds__(256) void k_f1(const ushort* __restrict__ hh, const ushort* __restrict__ hl,
                                            const ushort* __restrict__ eah, const ushort* __restrict__ eal,
                                            float* __restrict__ A) {
  int bid = blockIdx.x;                 // 1024 = b*256 + y
  int tid = threadIdx.x;
  int lane = tid & 63, wave = tid >> 6;
  int lm = lane & 15, lg = lane >> 4;
  int c = wave * 16 + lm;
  const ushort* hb = hh + (size_t)bid * 256 * 64;
  const ushort* lb = hl + (size_t)bid * 256 * 64;
  f32x4 acc[2];
  acc[0] = (f32x4){0.f, 0.f, 0.f, 0.f};
  acc[1] = (f32x4){0.f, 0.f, 0.f, 0.f};
#pragma unroll
  for (int kc = 0; kc < 8; ++kc) {
    int xb = kc * 32 + lg * 8;
    short8 bh, bl;
#pragma unroll
    for (int i = 0; i < 8; ++i) {
      bh[i] = (short)hb[(size_t)(xb + i) * 64 + c];
      bl[i] = (short)lb[(size_t)(xb + i) * 64 + c];
    }
#pragma unroll
    for (int mi = 0; mi < 2; ++mi) {
      int row = mi * 16 + lm;
      short8 ah = *(const short8*)&eah[row * 256 + xb];
      short8 al = *(const short8*)&eal[row * 256 + xb];
      acc[mi] = __builtin_amdgcn_mfma_f32_16x16x32_bf16(ah, bh, acc[mi], 0, 0, 0);
      acc[mi] = __builtin_amdgcn_mfma_f32_16x16x32_bf16(ah, bl, acc[mi], 0, 0, 0);
      acc[mi] = __builtin_amdgcn_mfma_f32_16x16x32_bf16(al, bh, acc[mi], 0, 0, 0);
    }
  }
  int b = bid >> 8, y = bid & 255;
  size_t rbase = ((size_t)(b * 64 + c) * 256 + y) * 32;
#pragma unroll
  for (int mi = 0; mi < 2; ++mi)
#pragma unroll
    for (int r = 0; r < 4; ++r) A[rbase + mi * 16 + lg * 4 + r] = acc[mi][r];
}

// ---------- F2: col DFT over y, LDS-staged (unchanged math, reads A old layout) ----------
__global__ __launch_bounds__(256) void k_f2(const float2* __restrict__ A, const float* __restrict__ cosT,
                                            const float* __restrict__ sinT, float2* __restrict__ X) {
  int plane = blockIdx.x;
  int tid = threadIdx.x;
  __shared__ float2 As[256 * 16];
  __shared__ float ct[16 * 257];
  __shared__ float stt[16 * 257];
  const float2* Ap = A + plane * 4096;
#pragma unroll
  for (int rep = 0; rep < 16; ++rep) {
    int flat = rep * 256 + tid;
    As[flat] = Ap[flat];
  }
#pragma unroll
  for (int rep = 0; rep < 16; ++rep) {
    int flat = rep * 256 + tid;
    int ky = flat >> 8, y = flat & 255;
    ct[ky * 257 + y] = cosT[flat];
    stt[ky * 257 + y] = sinT[flat];
  }
  __syncthreads();
  int ky = tid >> 4, kx = tid & 15;
  float xr = 0.f, xi = 0.f;
#pragma unroll 4
  for (int y = 0; y < 256; ++y) {
    float2 a = As[y * 16 + kx];
    float c = ct[ky * 257 + y], s = stt[ky * 257 + y];
    xr += c * a.x + s * a.y;
    xi += c * a.y - s * a.x;
  }
  X[plane * 256 + tid] = make_float2(xr, xi);
}

// ---------- MIX ----------
__global__ __launch_bounds__(256) void k_mix(const float2* __restrict__ X, const float* __restrict__ wr,
                                             const float* __restrict__ wi, float2* __restrict__ Y) {
  int o = blockIdx.x >> 2;
  int mc = blockIdx.x & 3;
  int tid = threadIdx.x;
  int cg = tid >> 6, m2 = tid & 63;
  int m = mc * 64 + m2;
  float yr[4] = {0.f, 0.f, 0.f, 0.f}, yi[4] = {0.f, 0.f, 0.f, 0.f};
#pragma unroll 4
  for (int cc = 0; cc < 16; ++cc) {
    int c = cg * 16 + cc;
    float r = wr[(c * 64 + o) * 256 + m];
    float im = wi[(c * 64 + o) * 256 + m];
#pragma unroll
    for (int b = 0; b < 4; ++b) {
      float2 xv = X[(b * 64 + c) * 256 + m];
      yr[b] += xv.x * r - xv.y * im;
      yi[b] += xv.x * im + xv.y * r;
    }
  }
  __shared__ float2 red[1024];
#pragma unroll
  for (int b = 0; b < 4; ++b) red[cg * 256 + b * 64 + m2] = make_float2(yr[b], yi[b]);
  __syncthreads();
  int b = tid >> 6;
  float sx = 0.f, sy = 0.f;
#pragma unroll
  for (int g2 = 0; g2 < 4; ++g2) {
    float2 v = red[g2 * 256 + b * 64 + m2];
    sx += v.x; sy += v.y;
  }
  Y[(b * 64 + o) * 256 + m] = make_float2(sx, sy);
}

// ---------- INV1: writes g split planes [b*64+o][y][32] ----------
__global__ __launch_bounds__(256) void k_inv1(const float2* __restrict__ Y, const float* __restrict__ cosT,
                                              const float* __restrict__ sinT,
                                              ushort* __restrict__ gh, ushort* __restrict__ gl) {
  int plane = blockIdx.x;               // 256 = B*O
  int y = threadIdx.x;
  __shared__ float2 Ys[256];
  Ys[threadIdx.x] = Y[plane * 256 + threadIdx.x];
  __syncthreads();
  float gr[16], gi[16];
#pragma unroll
  for (int k = 0; k < 16; ++k) { gr[k] = 0.f; gi[k] = 0.f; }
  for (int ky = 0; ky < 16; ++ky) {
    float c = cosT[ky * 256 + y], s = sinT[ky * 256 + y];
#pragma unroll
    for (int kx = 0; kx < 16; ++kx) {
      float2 v = Ys[ky * 16 + kx];
      gr[kx] += c * v.x - s * v.y;
      gi[kx] += c * v.y + s * v.x;
    }
  }
  float val[32];
  const float sc = 1.0f / 65536.0f;
#pragma unroll
  for (int kx = 0; kx < 16; ++kx) {
    float m = (kx == 0) ? sc : 2.0f * sc;
    val[2 * kx] = gr[kx] * m;
    val[2 * kx + 1] = gi[kx] * m;
  }
  size_t gb = ((size_t)plane * 256 + y) * 32;
#pragma unroll
  for (int q = 0; q < 8; ++q) {
    ushort4 H, L;
#pragma unroll
    for (int r = 0; r < 4; ++r) {
      float v = val[q * 4 + r];
      unsigned hi = bf16rne(v);
      ((ushort*)&H)[r] = (ushort)hi;
      ((ushort*)&L)[r] = (ushort)bf16rne(v - bf16tof(hi));
    }
    *(ushort4*)&gh[gb + q * 4] = H;
    *(ushort4*)&gl[gb + q * 4] = L;
  }
}

// ---------- K_LAYER (pure MFMA, no LDS): hout = GELU( [W | g] x [h ; ET] + wb ) ----------
// Block=(b,y,xh). M=64 o, N=128 x, K=96. All operands pre-split 16B loads.
__global__ __launch_bounds__(256) void k_layer(const ushort* __restrict__ hh, const ushort* __restrict__ hl,
                                               const ushort* __restrict__ gh, const ushort* __restrict__ gl,
                                               const ushort* __restrict__ wh, const ushort* __restrict__ wl,
                                               const float* __restrict__ wb,
                                               const ushort* __restrict__ e2h, const ushort* __restrict__ e2l,
                                               ushort* __restrict__ oh, ushort* __restrict__ ol) {
  int bid = blockIdx.x;                 // 2048 = b*512 + y*2 + xh
  int b = bid >> 9, y = (bid >> 1) & 255, xh = bid & 1;
  int tid = threadIdx.x;
  int lane = tid & 63, wave = tid >> 6;
  int lm = lane & 15, lg = lane >> 4;
  int x0 = xh * 128 + wave * 32;
  size_t nbase = (size_t)(b * 256 + y) * 256;

  f32x4 acc[4][2];
#pragma unroll
  for (int mi = 0; mi < 4; ++mi)
#pragma unroll
    for (int ni = 0; ni < 2; ++ni) acc[mi][ni] = (f32x4){0.f, 0.f, 0.f, 0.f};

#pragma unroll
  for (int kc = 0; kc < 2; ++kc) {
    short8 bh[2], bl[2];
#pragma unroll
    for (int ni = 0; ni < 2; ++ni) {
      size_t a = (nbase + x0 + ni * 16 + lm) * 64 + kc * 32 + lg * 8;
      bh[ni] = *(const short8*)&hh[a];
      bl[ni] = *(const short8*)&hl[a];
    }
#pragma unroll
    for (int mi = 0; mi < 4; ++mi) {
      int o = mi * 16 + lm;
      short8 ah = *(const short8*)&wh[o * 64 + kc * 32 + lg * 8];
      short8 al = *(const short8*)&wl[o * 64 + kc * 32 + lg * 8];
#pragma unroll
      for (int ni = 0; ni < 2; ++ni) {
        acc[mi][ni] = __builtin_amdgcn_mfma_f32_16x16x32_bf16(ah, bh[ni], acc[mi][ni], 0, 0, 0);
        acc[mi][ni] = __builtin_amdgcn_mfma_f32_16x16x32_bf16(ah, bl[ni], acc[mi][ni], 0, 0, 0);
        acc[mi][ni] = __builtin_amdgcn_mfma_f32_16x16x32_bf16(al, bh[ni], acc[mi][ni], 0, 0, 0);
      }
    }
  }
  {
    short8 bh[2], bl[2];
#pragma unroll
    for (int ni = 0; ni < 2; ++ni) {
      int xx = x0 + ni * 16 + lm;
      bh[ni] = *(const short8*)&e2h[xx * 32 + lg * 8];
      bl[ni] = *(const short8*)&e2l[xx * 32 + lg * 8];
    }
#pragma unroll
    for (int mi = 0; mi < 4; ++mi) {
      int o = mi * 16 + lm;
      size_t ga = ((size_t)(b * 64 + o) * 256 + y) * 32 + lg * 8;
      short8 ah = *(const short8*)&gh[ga];
      short8 al = *(const short8*)&gl[ga];
#pragma unroll
      for (int ni = 0; ni < 2; ++ni) {
        acc[mi][ni] = __builtin_amdgcn_mfma_f32_16x16x32_bf16(ah, bh[ni], acc[mi][ni], 0, 0, 0);
        acc[mi][ni] = __builtin_amdgcn_mfma_f32_16x16x32_bf16(ah, bl[ni], acc[mi][ni], 0, 0, 0);
        acc[mi][ni] = __builtin_amdgcn_mfma_f32_16x16x32_bf16(al, bh[ni], acc[mi][ni], 0, 0, 0);
      }
    }
  }
  // epilogue: bias + GELU + split-store to next h planes
#pragma unroll
  for (int mi = 0; mi < 4; ++mi)
#pragma unroll
    for (int ni = 0; ni < 2; ++ni) {
      int xx = x0 + ni * 16 + lm;
      size_t nb = (nbase + xx) * 64 + mi * 16 + lg * 4;
      ushort4 H, L;
#pragma unroll
      for (int r = 0; r < 4; ++r) {
        int o = mi * 16 + lg * 4 + r;
        float ge = gelu(acc[mi][ni][r] + wb[o]);
        unsigned hi = bf16rne(ge);
        ((ushort*)&H)[r] = (ushort)hi;
        ((ushort*)&L)[r] = (ushort)bf16rne(ge - bf16tof(hi));
      }
      *(ushort4*)&oh[nb] = H;
      *(ushort4*)&ol[nb] = L;
    }
}

// ---------- K_FINAL (pure MFMA, no LDS): out = fc2( GELU( fc1(h) ) ) ----------
__global__ __launch_bounds__(256) void k_final(const ushort* __restrict__ hh, const ushort* __restrict__ hl,
                                               const ushort* __restrict__ w1h, const ushort* __restrict__ w1l,
                                               const float* __restrict__ b1, const float* __restrict__ w2,
                                               const float* __restrict__ b2, float* __restrict__ out) {
  int bid = blockIdx.x;                 // 2048 = b*512 + y*2 + xh
  int b = bid >> 9, y = (bid >> 1) & 255, xh = bid & 1;
  int tid = threadIdx.x;
  int lane = tid & 63, wave = tid >> 6;
  int lm = lane & 15, lg = lane >> 4;
  int x0 = xh * 128 + wave * 32;
  size_t nbase = (size_t)(b * 256 + y) * 256;

  f32x4 acc[8][2];
#pragma unroll
  for (int mi = 0; mi < 8; ++mi)
#pragma unroll
    for (int ni = 0; ni < 2; ++ni) acc[mi][ni] = (f32x4){0.f, 0.f, 0.f, 0.f};

#pragma unroll
  for (int kc = 0; kc < 2; ++kc) {
    short8 bh[2], bl[2];
#pragma unroll
    for (int ni = 0; ni < 2; ++ni) {
      size_t a = (nbase + x0 + ni * 16 + lm) * 64 + kc * 32 + lg * 8;
      bh[ni] = *(const short8*)&hh[a];
      bl[ni] = *(const short8*)&hl[a];
    }
#pragma unroll
    for (int mi = 0; mi < 8; ++mi) {
      int j = mi * 16 + lm;
      short8 ah = *(const short8*)&w1h[j * 64 + kc * 32 + lg * 8];
      short8 al = *(const short8*)&w1l[j * 64 + kc * 32 + lg * 8];
#pragma unroll
      for (int ni = 0; ni < 2; ++ni) {
        acc[mi][ni] = __builtin_amdgcn_mfma_f32_16x16x32_bf16(ah, bh[ni], acc[mi][ni], 0, 0, 0);
        acc[mi][ni] = __builtin_amdgcn_mfma_f32_16x16x32_bf16(ah, bl[ni], acc[mi][ni], 0, 0, 0);
        acc[mi][ni] = __builtin_amdgcn_mfma_f32_16x16x32_bf16(al, bh[ni], acc[mi][ni], 0, 0, 0);
      }
    }
  }

  float p0 = 0.f, p1 = 0.f;
#pragma unroll
  for (int mi = 0; mi < 8; ++mi)
#pragma unroll
    for (int r = 0; r < 4; ++r) {
      int j = mi * 16 + lg * 4 + r;
      float bj = b1[j], wj = w2[j];
      p0 += wj * gelu(acc[mi][0][r] + bj);
      p1 += wj * gelu(acc[mi][1][r] + bj);
    }
  p0 += __shfl_xor(p0, 16);
  p0 += __shfl_xor(p0, 32);
  p1 += __shfl_xor(p1, 16);
  p1 += __shfl_xor(p1, 32);
  if (lg == 0) {
    float bb2 = b2[0];
    int ob = (b * 256 + y) * 256 + x0;
    out[ob + lm] = p0 + bb2;
    out[ob + 16 + lm] = p1 + bb2;
  }
}

extern "C" void kernel_launch(void* const* d_in, const int* in_sizes, int n_in,
                              void* d_out, int out_size, void* d_ws, size_t ws_size,
                              hipStream_t stream) {
  const float* x       = (const float*)d_in[0];
  const float* fc0_w   = (const float*)d_in[1];
  const float* fc0_b   = (const float*)d_in[2];
  const float* spec_wr = (const float*)d_in[3];
  const float* spec_wi = (const float*)d_in[4];
  const float* w_w     = (const float*)d_in[5];
  const float* w_b     = (const float*)d_in[6];
  const float* fc1_w   = (const float*)d_in[7];
  const float* fc1_b   = (const float*)d_in[8];
  const float* fc2_w   = (const float*)d_in[9];
  const float* fc2_b   = (const float*)d_in[10];
  float* out = (float*)d_out;

  char* ws = (char*)d_ws;
  ushort* h0h  = (ushort*)ws;                              // 33554432 B
  ushort* h0l  = (ushort*)(ws + 33554432);                 // 33554432 B
  ushort* h1h  = (ushort*)(ws + 67108864);                 // 33554432 B
  ushort* h1l  = (ushort*)(ws + 100663296);                // 33554432 B
  float*  A    = (float*)(ws + 134217728);                 // 8388608 B
  ushort* gh   = (ushort*)(ws + 142606336);                // 4194304 B
  ushort* gl   = (ushort*)(ws + 146800640);                // 4194304 B
  float2* X    = (float2*)(ws + 150994944);                // 524288 B
  float2* Y    = (float2*)(ws + 151519232);                // 524288 B
  float*  cosT = (float*)(ws + 152043520);                 // 16384 B
  float*  sinT = (float*)(ws + 152059904);                 // 16384 B
  ushort* eah  = (ushort*)(ws + 152076288);                // 16384 B
  ushort* eal  = (ushort*)(ws + 152092672);                // 16384 B
  ushort* e2h  = (ushort*)(ws + 152109056);                // 16384 B
  ushort* e2l  = (ushort*)(ws + 152125440);                // 16384 B
  ushort* wWh  = (ushort*)(ws + 152141824);                // 32768 B
  ushort* wWl  = (ushort*)(ws + 152174592);                // 32768 B
  ushort* w1h  = (ushort*)(ws + 152207360);                // 16384 B
  ushort* w1l  = (ushort*)(ws + 152223744);                // 16384 B

  k_tables<<<48, 256, 0, stream>>>(cosT, sinT, eah, eal, e2h, e2l);
  k_wsplit<<<96, 256, 0, stream>>>(w_w, fc1_w, wWh, wWl, w1h, w1l);
  k_fc0<<<1024, 256, 0, stream>>>(x, fc0_w, fc0_b, h0h, h0l);
  ushort* hch = h0h; ushort* hcl = h0l;
  ushort* hnh = h1h; ushort* hnl = h1l;
  for (int l = 0; l < 4; ++l) {
    k_f1<<<1024, 256, 0, stream>>>(hch, hcl, eah, eal, A);
    k_f2<<<256, 256, 0, stream>>>((const float2*)A, cosT, sinT, X);
    k_mix<<<256, 256, 0, stream>>>(X, spec_wr + (size_t)l * 1048576, spec_wi + (size_t)l * 1048576, Y);
    k_inv1<<<256, 256, 0, stream>>>(Y, cosT, sinT, gh, gl);
    k_layer<<<2048, 256, 0, stream>>>(hch, hcl, gh, gl, wWh + l * 4096, wWl + l * 4096,
                                      w_b + l * 64, e2h, e2l, hnh, hnl);
    ushort* t;
    t = hch; hch = hnh; hnh = t;
    t = hcl; hcl = hnl; hnl = t;
  }
  k_final<<<2048, 256, 0, stream>>>(hch, hcl, w1h, w1l, fc1_b, fc2_w, fc2_b, out);
}